// Round 2
// baseline (457.247 us; speedup 1.0000x reference)
//
#include <hip/hip_runtime.h>
#include <math.h>

#define B 2
#define C 128
#define SL 3136      // 56*56
#define VOL 175616   // 56^3
#define S512 512
#define EPS 1e-5f
#define PCL 14336    // B*C*56

// workspace layout (float offsets)
#define OFF_POOL 0            // 3*PCL: x_d, x_h, x_w (combined, scaled)
#define OFF_PPH  43008        // B*C*8*56 = 114688 partial h-sums
#define OFF_PPW  157696       // 114688 partial w-sums
#define OFF_GATE 272384       // 3*PCL (gd, gh, gw)
#define OFF_Y    315392       // B*C*512
#define OFF_STAT 446464       // 4
#define OFF_CA   446468       // B*C

#define F4SUM(v) ((v).x + (v).y + (v).z + (v).w)

// ---------------- K1: axis pools (partial) ----------------
// grid (8, C, B); block 256. Block owns 7 d-slices of one (b,c).
__global__ __launch_bounds__(256) void k1_pool(const float* __restrict__ x,
                                               float* __restrict__ ws) {
    int dd = blockIdx.x, c = blockIdx.y, b = blockIdx.z;
    int bc = b * C + c;
    const float4* base = (const float4*)(x + (size_t)bc * VOL) + dd * 7 * 784;
    int t = threadIdx.x;
    int lane = t & 63, wave = t >> 6;
    __shared__ float s_h[56];
    __shared__ float s_w[56];
    __shared__ float s_dred[7 * 4];
    if (t < 56) { s_h[t] = 0.f; s_w[t] = 0.f; }
    __syncthreads();
    float4 a0 = make_float4(0,0,0,0), a1 = make_float4(0,0,0,0);
    float4 a2 = make_float4(0,0,0,0), a3 = make_float4(0,0,0,0);
    #pragma unroll
    for (int dz = 0; dz < 7; ++dz) {
        const float4* sp = base + dz * 784;
        float4 v0 = sp[t];
        float4 v1 = sp[t + 256];
        float4 v2 = sp[t + 512];
        float4 v3 = make_float4(0,0,0,0);
        if (t < 16) v3 = sp[t + 768];
        a0.x += v0.x; a0.y += v0.y; a0.z += v0.z; a0.w += v0.w;
        a1.x += v1.x; a1.y += v1.y; a1.z += v1.z; a1.w += v1.w;
        a2.x += v2.x; a2.y += v2.y; a2.z += v2.z; a2.w += v2.w;
        a3.x += v3.x; a3.y += v3.y; a3.z += v3.z; a3.w += v3.w;
        float s4 = F4SUM(v0) + F4SUM(v1) + F4SUM(v2) + F4SUM(v3);
        #pragma unroll
        for (int off = 1; off < 64; off <<= 1) s4 += __shfl_xor(s4, off);
        if (lane == 0) s_dred[dz * 4 + wave] = s4;
    }
    {
        int s0 = t, s1 = t + 256, s2 = t + 512;
        atomicAdd(&s_h[s0 / 14], F4SUM(a0));
        atomicAdd(&s_h[s1 / 14], F4SUM(a1));
        atomicAdd(&s_h[s2 / 14], F4SUM(a2));
        int w0 = (s0 % 14) * 4, w1 = (s1 % 14) * 4, w2 = (s2 % 14) * 4;
        atomicAdd(&s_w[w0 + 0], a0.x); atomicAdd(&s_w[w0 + 1], a0.y);
        atomicAdd(&s_w[w0 + 2], a0.z); atomicAdd(&s_w[w0 + 3], a0.w);
        atomicAdd(&s_w[w1 + 0], a1.x); atomicAdd(&s_w[w1 + 1], a1.y);
        atomicAdd(&s_w[w1 + 2], a1.z); atomicAdd(&s_w[w1 + 3], a1.w);
        atomicAdd(&s_w[w2 + 0], a2.x); atomicAdd(&s_w[w2 + 1], a2.y);
        atomicAdd(&s_w[w2 + 2], a2.z); atomicAdd(&s_w[w2 + 3], a2.w);
        if (t < 16) {
            int s3 = t + 768, w3 = (s3 % 14) * 4;
            atomicAdd(&s_h[s3 / 14], F4SUM(a3));
            atomicAdd(&s_w[w3 + 0], a3.x); atomicAdd(&s_w[w3 + 1], a3.y);
            atomicAdd(&s_w[w3 + 2], a3.z); atomicAdd(&s_w[w3 + 3], a3.w);
        }
    }
    __syncthreads();
    if (t < 7) {
        float ds = s_dred[t * 4] + s_dred[t * 4 + 1] + s_dred[t * 4 + 2] + s_dred[t * 4 + 3];
        ws[OFF_POOL + bc * 56 + dd * 7 + t] = ds * (1.0f / 3136.0f);
    }
    if (t < 56) {
        ws[OFF_PPH + (bc * 8 + dd) * 56 + t] = s_h[t];
        ws[OFF_PPW + (bc * 8 + dd) * 56 + t] = s_w[t];
    }
}

// ---------------- K1b: combine partial h/w sums ----------------
// grid 112 x 256 : 28672 = 2 * B*C*56 elements
__global__ __launch_bounds__(256) void k1b_combine(float* __restrict__ ws) {
    int idx = blockIdx.x * 256 + threadIdx.x;
    int axis = idx / 14336, rem = idx % 14336;
    int bc = rem / 56, pos = rem % 56;
    const float* p = ws + (axis ? OFF_PPW : OFF_PPH) + bc * 8 * 56 + pos;
    float s = 0.f;
    #pragma unroll
    for (int dd = 0; dd < 8; ++dd) s += p[dd * 56];
    ws[OFF_POOL + (1 + axis) * PCL + bc * 56 + pos] = s * (1.0f / 3136.0f);
}

// ---------------- K2: gates (conv + GN(4) + sigmoid) ----------------
// grid = 24: blockIdx.x = sg*8 + b*4 + g
__global__ __launch_bounds__(256) void k2_gate(
    const float* __restrict__ w0, const float* __restrict__ b0,
    const float* __restrict__ w1, const float* __restrict__ b1,
    const float* __restrict__ w2, const float* __restrict__ b2,
    const float* __restrict__ w3, const float* __restrict__ b3,
    const float* __restrict__ g0, const float* __restrict__ be0,
    const float* __restrict__ g1, const float* __restrict__ be1,
    const float* __restrict__ g2, const float* __restrict__ be2,
    float* __restrict__ ws) {
    int idx = blockIdx.x;
    int sg = idx >> 3, rem = idx & 7;
    int b = rem >> 2, g = rem & 3;
    const float* wconv[4] = {w0, w1, w2, w3};
    const float* bconv[4] = {b0, b1, b2, b3};
    const float* gam[3] = {g0, g1, g2};
    const float* bet[3] = {be0, be1, be2};
    const int ksz[4] = {3, 5, 7, 9};
    int kg = ksz[g];
    int half = kg >> 1;
    __shared__ float s_in[32 * 56];
    __shared__ float s_wt[32 * 9];
    __shared__ float s_b[32];
    __shared__ float s_redu[8];
    int t = threadIdx.x;
    const float* sp = ws + OFF_POOL + sg * PCL + (b * C + g * 32) * 56;
    for (int e = t; e < 1792; e += 256) s_in[e] = sp[e];
    for (int e = t; e < 32 * kg; e += 256) s_wt[e] = wconv[g][e];
    if (t < 32) s_b[t] = bconv[g][t];
    __syncthreads();
    float vals[7];
    float sum = 0.f, sq = 0.f;
    {
        int ii = 0;
        for (int e = t; e < 1792; e += 256, ++ii) {
            int cl = e / 56, l = e % 56;
            float acc = s_b[cl];
            for (int tt = 0; tt < kg; ++tt) {
                int ll = l + tt - half;
                if (ll >= 0 && ll < 56) acc += s_in[cl * 56 + ll] * s_wt[cl * kg + tt];
            }
            vals[ii] = acc;
            sum += acc; sq += acc * acc;
        }
    }
    #pragma unroll
    for (int off = 1; off < 64; off <<= 1) {
        sum += __shfl_xor(sum, off);
        sq += __shfl_xor(sq, off);
    }
    int lane = t & 63, wv_ = t >> 6;
    if (lane == 0) { s_redu[wv_] = sum; s_redu[4 + wv_] = sq; }
    __syncthreads();
    sum = s_redu[0] + s_redu[1] + s_redu[2] + s_redu[3];
    sq = s_redu[4] + s_redu[5] + s_redu[6] + s_redu[7];
    float mean = sum / 1792.0f;
    float var = sq / 1792.0f - mean * mean;
    float rs = rsqrtf(var + EPS);
    float* gp = ws + OFF_GATE + sg * PCL + (b * C + g * 32) * 56;
    const float* ga = gam[sg];
    const float* be = bet[sg];
    {
        int ii = 0;
        for (int e = t; e < 1792; e += 256, ++ii) {
            int cl = e / 56;
            int cch = g * 32 + cl;
            float xn = (vals[ii] - mean) * rs * ga[cch] + be[cch];
            gp[e] = 1.0f / (1.0f + expf(-xn));
        }
    }
}

// ---------------- K3: gated 7^3 avg-pool -> y ----------------
// grid (8, C, B); block 256. threads 0..63 own (hh,ww).
__global__ __launch_bounds__(256) void k3_pooly(const float* __restrict__ x,
                                               float* __restrict__ ws) {
    int dd = blockIdx.x, c = blockIdx.y, b = blockIdx.z;
    int bc = b * C + c;
    __shared__ float xs[SL];
    __shared__ float s_gh[56];
    __shared__ float s_gw[56];
    int t = threadIdx.x;
    const float* gp = ws + OFF_GATE;
    if (t < 56) s_gh[t] = gp[1 * PCL + bc * 56 + t];
    else if (t < 112) s_gw[t - 56] = gp[2 * PCL + bc * 56 + (t - 56)];
    float acc = 0.f;
    const float* xp = x + (size_t)bc * VOL + (size_t)dd * 7 * SL;
    int hh = (t & 63) >> 3, ww = t & 7;
    for (int dz = 0; dz < 7; ++dz) {
        __syncthreads();
        const float4* src = (const float4*)(xp + dz * SL);
        float4* dst = (float4*)xs;
        for (int e = t; e < 784; e += 256) dst[e] = src[e];
        __syncthreads();
        if (t < 64) {
            float part = 0.f;
            for (int r = 0; r < 7; ++r) {
                int h_ = hh * 7 + r;
                const float* row = &xs[h_ * 56 + ww * 7];
                float rsum = 0.f;
                #pragma unroll
                for (int q = 0; q < 7; ++q) rsum += row[q] * s_gw[ww * 7 + q];
                part += s_gh[h_] * rsum;
            }
            acc += part * gp[0 * PCL + bc * 56 + dd * 7 + dz];
        }
    }
    if (t < 64) ws[OFF_Y + bc * S512 + dd * 64 + t] = acc * (1.0f / 343.0f);
}

// ---------------- K4a: per-batch GN(1) stats over y ----------------
__global__ __launch_bounds__(1024) void k4a_stats(float* __restrict__ ws) {
    int b = blockIdx.x;
    const float4* yp = (const float4*)(ws + OFF_Y + b * 65536);
    int t = threadIdx.x;
    float sum = 0.f, sq = 0.f;
    #pragma unroll
    for (int k = 0; k < 16; ++k) {
        float4 v = yp[t + k * 1024];
        sum += F4SUM(v);
        sq += v.x * v.x + v.y * v.y + v.z * v.z + v.w * v.w;
    }
    __shared__ float s_redu[32];
    #pragma unroll
    for (int off = 1; off < 64; off <<= 1) {
        sum += __shfl_xor(sum, off);
        sq += __shfl_xor(sq, off);
    }
    int lane = t & 63, wv_ = t >> 6;
    if (lane == 0) { s_redu[wv_] = sum; s_redu[16 + wv_] = sq; }
    __syncthreads();
    if (t == 0) {
        sum = 0.f; sq = 0.f;
        #pragma unroll
        for (int k = 0; k < 16; ++k) { sum += s_redu[k]; sq += s_redu[16 + k]; }
        float mean = sum / 65536.0f;
        float var = sq / 65536.0f - mean * mean;
        ws[OFF_STAT + b * 2] = mean;
        ws[OFF_STAT + b * 2 + 1] = rsqrtf(var + EPS);
    }
}

// ---------------- K4b: per-(b,head) channel attention -> ca ----------------
__global__ __launch_bounds__(256) void k4b_attn(
    const float* __restrict__ gn, const float* __restrict__ btn,
    const float* __restrict__ wq, const float* __restrict__ wk,
    const float* __restrict__ wv, float* __restrict__ ws) {
    int blk = blockIdx.x;
    int b = blk >> 3, hd = blk & 7;
    __shared__ float yn[16 * 516];
    __shared__ float s_sc[256];
    __shared__ float s_ybar[16];
    int t = threadIdx.x;
    float mean = ws[OFF_STAT + b * 2];
    float rs = ws[OFF_STAT + b * 2 + 1];
    const float* yp = ws + OFF_Y + b * 65536 + hd * 8192;
    for (int e = t; e < 8192; e += 256) {
        int i = e >> 9, s = e & 511;
        int cch = hd * 16 + i;
        yn[i * 516 + s] = (yp[e] - mean) * rs * gn[cch] + btn[cch];
    }
    __syncthreads();
    int i = t >> 4, j = t & 15;
    const float4* ri = (const float4*)&yn[i * 516];
    const float4* rj = (const float4*)&yn[j * 516];
    float g = 0.f;
    #pragma unroll 4
    for (int s = 0; s < 128; ++s) {
        float4 a = ri[s], c = rj[s];
        g += a.x * c.x + a.y * c.y + a.z * c.z + a.w * c.w;
    }
    s_sc[t] = wq[hd * 16 + i] * wk[hd * 16 + j] * 0.25f * g;
    if (t < 16) {
        const float4* r = (const float4*)&yn[t * 516];
        float sx = 0.f, sy = 0.f, sz = 0.f, sw = 0.f;
        #pragma unroll 4
        for (int s = 0; s < 128; ++s) {
            float4 a = r[s];
            sx += a.x; sy += a.y; sz += a.z; sw += a.w;
        }
        s_ybar[t] = (sx + sy + sz + sw) * (1.0f / 512.0f);
    }
    __syncthreads();
    if (t < 16) {
        float m = -1e30f;
        #pragma unroll
        for (int jj = 0; jj < 16; ++jj) m = fmaxf(m, s_sc[t * 16 + jj]);
        float den = 0.f, num = 0.f;
        #pragma unroll
        for (int jj = 0; jj < 16; ++jj) {
            float e = expf(s_sc[t * 16 + jj] - m);
            den += e;
            num += e * wv[hd * 16 + jj] * s_ybar[jj];
        }
        float o = num / den;
        ws[OFF_CA + b * C + hd * 16 + t] = 1.0f / (1.0f + expf(-o));
    }
}

// ---------------- K5: out = ca * gd*gh*gw * x ----------------
// grid (14, C, B); block 256; 4 d-slices per block
__global__ __launch_bounds__(256) void k5_out(const float* __restrict__ x,
                                              const float* __restrict__ ws,
                                              float* __restrict__ out) {
    int d4 = blockIdx.x, c = blockIdx.y, b = blockIdx.z;
    int bc = b * C + c;
    int t = threadIdx.x;
    __shared__ float s_gh[56];
    __shared__ float4 s_gw4[14];
    __shared__ float s_gd[4];
    const float* gp = ws + OFF_GATE;
    if (t < 56) s_gh[t] = gp[1 * PCL + bc * 56 + t];
    else if (t < 70) s_gw4[t - 56] = ((const float4*)(gp + 2 * PCL + bc * 56))[t - 56];
    else if (t < 74) s_gd[t - 70] = gp[0 * PCL + bc * 56 + d4 * 4 + (t - 70)] * ws[OFF_CA + bc];
    __syncthreads();
    const float4* xp = (const float4*)(x + (size_t)bc * VOL) + d4 * 4 * 784;
    float4* op = (float4*)(out + (size_t)bc * VOL) + d4 * 4 * 784;
    #pragma unroll
    for (int i = 0; i < 4; ++i) {
        float gd = s_gd[i];
        #pragma unroll
        for (int k = 0; k < 3; ++k) {
            int e = t + k * 256;
            float4 v = xp[i * 784 + e];
            float fh = gd * s_gh[e / 14];
            float4 gw = s_gw4[e % 14];
            v.x *= fh * gw.x; v.y *= fh * gw.y; v.z *= fh * gw.z; v.w *= fh * gw.w;
            op[i * 784 + e] = v;
        }
        if (t < 16) {
            int e = t + 768;
            float4 v = xp[i * 784 + e];
            float fh = gd * s_gh[e / 14];
            float4 gw = s_gw4[e % 14];
            v.x *= fh * gw.x; v.y *= fh * gw.y; v.z *= fh * gw.z; v.w *= fh * gw.w;
            op[i * 784 + e] = v;
        }
    }
}

extern "C" void kernel_launch(void* const* d_in, const int* in_sizes, int n_in,
                              void* d_out, int out_size, void* d_ws, size_t ws_size,
                              hipStream_t stream) {
    const float* x = (const float*)d_in[0];
    float* ws = (float*)d_ws;
    float* out = (float*)d_out;

    k1_pool<<<dim3(8, C, B), 256, 0, stream>>>(x, ws);
    k1b_combine<<<112, 256, 0, stream>>>(ws);
    k2_gate<<<24, 256, 0, stream>>>(
        (const float*)d_in[1], (const float*)d_in[2],
        (const float*)d_in[3], (const float*)d_in[4],
        (const float*)d_in[5], (const float*)d_in[6],
        (const float*)d_in[7], (const float*)d_in[8],
        (const float*)d_in[9], (const float*)d_in[10],
        (const float*)d_in[11], (const float*)d_in[12],
        (const float*)d_in[13], (const float*)d_in[14],
        ws);
    k3_pooly<<<dim3(8, C, B), 256, 0, stream>>>(x, ws);
    k4a_stats<<<2, 1024, 0, stream>>>(ws);
    k4b_attn<<<16, 256, 0, stream>>>(
        (const float*)d_in[15], (const float*)d_in[16],
        (const float*)d_in[17], (const float*)d_in[18],
        (const float*)d_in[19], ws);
    k5_out<<<dim3(14, C, B), 256, 0, stream>>>(x, ws, out);
}